// Round 1
// baseline (2390.932 us; speedup 1.0000x reference)
//
#include <hip/hip_runtime.h>

#define N_NODES 100000
#define N_EDGES 1250000
#define F 64

// Phase 1: edge scatter. 16 threads per edge; each thread handles 4 features
// (one float4 of the 64-float source row). 8 atomicAdds per thread
// (4 floats x 2 directions). Gather of x rows is coalesced per 16-lane group.
__global__ __launch_bounds__(256) void scatter_kernel(
    const float4* __restrict__ x4,   // [N_NODES, 16] as float4
    const int*    __restrict__ ei,   // [2, E] flat: senders then receivers
    const float*  __restrict__ ew,   // [2, E, 1] flat: ew_s2d then ew_d2s
    float* __restrict__ aggA,        // d_out[0 : N*F)      (will become out_s2d)
    float* __restrict__ aggB)        // d_out[N*F : 2*N*F)  (will become out_d2s)
{
    int t = blockIdx.x * blockDim.x + threadIdx.x;
    int e = t >> 4;
    int lane16 = t & 15;
    if (e >= N_EDGES) return;

    int   src = ei[e];
    int   dst = ei[N_EDGES + e];
    float w0  = ew[e];             // ew_s2d
    float w1  = ew[N_EDGES + e];   // ew_d2s

    float4 v = x4[(size_t)src * 16 + lane16];

    int base = dst * F + lane16 * 4;
    atomicAdd(&aggA[base + 0], v.x * w0);
    atomicAdd(&aggA[base + 1], v.y * w0);
    atomicAdd(&aggA[base + 2], v.z * w0);
    atomicAdd(&aggA[base + 3], v.w * w0);
    atomicAdd(&aggB[base + 0], v.x * w1);
    atomicAdd(&aggB[base + 1], v.y * w1);
    atomicAdd(&aggB[base + 2], v.z * w1);
    atomicAdd(&aggB[base + 3], v.w * w1);
}

// Phase 2: per-row 64x64 matmul + bias, in place on d_out.
// One wave per node row; lane = output feature j. The agg row is read into
// registers first (same lane reads then writes the same element -> safe
// in-place). W tiles staged in LDS; row element k broadcast via __shfl.
__global__ __launch_bounds__(256) void matmul_kernel(
    float* __restrict__ outA, float* __restrict__ outB,
    const float* __restrict__ Wsrc, const float* __restrict__ Wdst,
    const float* __restrict__ bsrc, const float* __restrict__ bdst)
{
    __shared__ float lWs[F * F];
    __shared__ float lWd[F * F];

    const float4* Ws4 = (const float4*)Wsrc;
    const float4* Wd4 = (const float4*)Wdst;
    float4* lWs4 = (float4*)lWs;
    float4* lWd4 = (float4*)lWd;
    for (int i = threadIdx.x; i < F * F / 4; i += blockDim.x) {
        lWs4[i] = Ws4[i];
        lWd4[i] = Wd4[i];
    }
    __syncthreads();

    int wave = (blockIdx.x * blockDim.x + threadIdx.x) >> 6;
    int lane = threadIdx.x & 63;
    if (wave >= N_NODES) return;

    size_t rowbase = (size_t)wave * F;
    float a0 = outA[rowbase + lane];
    float a1 = outB[rowbase + lane];
    float acc0 = bsrc[lane];
    float acc1 = bdst[lane];

    #pragma unroll
    for (int k = 0; k < F; ++k) {
        float s0 = __shfl(a0, k);
        float s1 = __shfl(a1, k);
        acc0 += s0 * lWs[k * F + lane];
        acc1 += s1 * lWd[k * F + lane];
    }

    outA[rowbase + lane] = acc0;
    outB[rowbase + lane] = acc1;
}

extern "C" void kernel_launch(void* const* d_in, const int* in_sizes, int n_in,
                              void* d_out, int out_size, void* d_ws, size_t ws_size,
                              hipStream_t stream) {
    const float* x    = (const float*)d_in[0];
    const int*   ei   = (const int*)d_in[1];
    const float* ew   = (const float*)d_in[2];
    const float* Wsrc = (const float*)d_in[3];
    const float* Wdst = (const float*)d_in[4];
    const float* bsrc = (const float*)d_in[5];
    const float* bdst = (const float*)d_in[6];

    float* out  = (float*)d_out;
    float* outA = out;                          // out_s2d region (agg first)
    float* outB = out + (size_t)N_NODES * F;    // out_d2s region

    // d_out doubles as the aggregation buffer; zero it (poisoned 0xAA).
    hipMemsetAsync(d_out, 0, (size_t)out_size * sizeof(float), stream);

    const int threads = 256;
    int blocks_scatter = (N_EDGES * 16 + threads - 1) / threads;  // 78125
    scatter_kernel<<<blocks_scatter, threads, 0, stream>>>(
        (const float4*)x, ei, ew, outA, outB);

    int blocks_mm = (N_NODES * 64 + threads - 1) / threads;       // 25000
    matmul_kernel<<<blocks_mm, threads, 0, stream>>>(
        outA, outB, Wsrc, Wdst, bsrc, bdst);
}

// Round 2
// 362.864 us; speedup vs baseline: 6.5891x; 6.5891x over previous
//
#include <hip/hip_runtime.h>

#define N_NODES 100000
#define N_EDGES 1250000
#define F 64
#define SCAN_CHUNK 1024
#define NBLK_SCAN ((N_NODES + SCAN_CHUNK - 1) / SCAN_CHUNK)  // 98

// ---------------- CSR-build path ----------------

// K1: histogram of receivers. 1.25M int atomics over 100K counters (~12.5 avg).
__global__ __launch_bounds__(256) void hist_kernel(const int* __restrict__ ei,
                                                   int* __restrict__ counts) {
    int e = blockIdx.x * 256 + threadIdx.x;
    if (e < N_EDGES) atomicAdd(&counts[ei[N_EDGES + e]], 1);
}

// K2a: per-1024-chunk partial sums of counts.
__global__ __launch_bounds__(256) void scan_reduce_kernel(const int* __restrict__ counts,
                                                          int* __restrict__ partials) {
    int base = blockIdx.x * SCAN_CHUNK + threadIdx.x * 4;
    int s = 0;
    if (base + 3 < N_NODES) {  // N_NODES % 4 == 0, whole-thread guard is exact
        int4 c = *(const int4*)&counts[base];
        s = c.x + c.y + c.z + c.w;
    }
    for (int d = 32; d > 0; d >>= 1) s += __shfl_down(s, d);
    __shared__ int lds[4];
    int lane = threadIdx.x & 63, wave = threadIdx.x >> 6;
    if (lane == 0) lds[wave] = s;
    __syncthreads();
    if (threadIdx.x == 0) partials[blockIdx.x] = lds[0] + lds[1] + lds[2] + lds[3];
}

// K2b: exclusive scan of the 98 partials (tiny; single thread).
__global__ void scan_partials_kernel(int* __restrict__ partials) {
    if (blockIdx.x == 0 && threadIdx.x == 0) {
        int run = 0;
        for (int i = 0; i < NBLK_SCAN; ++i) { int v = partials[i]; partials[i] = run; run += v; }
    }
}

// K2c: per-chunk exclusive scan + chunk offset -> CSR offsets; also init cursor.
__global__ __launch_bounds__(256) void scan_apply_kernel(const int* __restrict__ counts,
                                                         const int* __restrict__ partials,
                                                         int* __restrict__ off,
                                                         int* __restrict__ cursor) {
    int base = blockIdx.x * SCAN_CHUNK + threadIdx.x * 4;
    int4 c = {0, 0, 0, 0};
    bool act = (base + 3 < N_NODES);
    if (act) c = *(const int4*)&counts[base];
    int s = c.x + c.y + c.z + c.w;

    // block-exclusive scan of per-thread sums
    int lane = threadIdx.x & 63, wave = threadIdx.x >> 6;
    int x = s;
    for (int d = 1; d < 64; d <<= 1) {
        int y = __shfl_up(x, d);
        if (lane >= d) x += y;
    }
    __shared__ int wsum[4];
    if (lane == 63) wsum[wave] = x;
    __syncthreads();
    int pre = x - s;
    for (int w = 0; w < wave; ++w) pre += wsum[w];
    pre += partials[blockIdx.x];

    if (act) {
        int o0 = pre, o1 = o0 + c.x, o2 = o1 + c.y, o3 = o2 + c.z;
        int4 o = {o0, o1, o2, o3};
        *(int4*)&off[base] = o;
        *(int4*)&cursor[base] = o;
        if (base + 4 == N_NODES) off[N_NODES] = o3 + c.w;  // == N_EDGES
    }
}

// K3: scatter edge payloads into receiver-sorted order.
__global__ __launch_bounds__(256) void permute_kernel(const int* __restrict__ ei,
                                                      const float* __restrict__ ew,
                                                      int* __restrict__ cursor,
                                                      int* __restrict__ sSrc,
                                                      float2* __restrict__ sW) {
    int e = blockIdx.x * 256 + threadIdx.x;
    if (e >= N_EDGES) return;
    int r = ei[N_EDGES + e];
    int pos = atomicAdd(&cursor[r], 1);
    sSrc[pos] = ei[e];
    sW[pos] = make_float2(ew[e], ew[N_EDGES + e]);
}

// K4: wave-per-node aggregation. lane = feature. Each agg row written ONCE.
__global__ __launch_bounds__(256) void agg_kernel(const float* __restrict__ x,
                                                  const int* __restrict__ off,
                                                  const int* __restrict__ sSrc,
                                                  const float2* __restrict__ sW,
                                                  float* __restrict__ aggA,
                                                  float* __restrict__ aggB) {
    int n = blockIdx.x * 4 + (threadIdx.x >> 6);
    int lane = threadIdx.x & 63;
    if (n >= N_NODES) return;
    int beg = off[n], end = off[n + 1];
    float acc0 = 0.f, acc1 = 0.f, acc0b = 0.f, acc1b = 0.f;
    int i = beg;
    for (; i + 1 < end; i += 2) {  // unroll x2 for MLP
        int s0 = sSrc[i], s1 = sSrc[i + 1];
        float2 w0 = sW[i], w1 = sW[i + 1];
        float v0 = x[(size_t)s0 * F + lane];
        float v1 = x[(size_t)s1 * F + lane];
        acc0 += v0 * w0.x; acc1 += v0 * w0.y;
        acc0b += v1 * w1.x; acc1b += v1 * w1.y;
    }
    if (i < end) {
        int s0 = sSrc[i];
        float2 w0 = sW[i];
        float v0 = x[(size_t)s0 * F + lane];
        acc0 += v0 * w0.x; acc1 += v0 * w0.y;
    }
    size_t rb = (size_t)n * F + lane;
    aggA[rb] = acc0 + acc0b;
    aggB[rb] = acc1 + acc1b;
}

// K5: register-tiled [64-node x 64-feat] GEMM + bias, in place on d_out.
// blockIdx.y selects direction. Thread = 4 nodes x 4 feats.
__global__ __launch_bounds__(256) void gemm_kernel(float* __restrict__ outA,
                                                   float* __restrict__ outB,
                                                   const float* __restrict__ Wsrc,
                                                   const float* __restrict__ Wdst,
                                                   const float* __restrict__ bsrc,
                                                   const float* __restrict__ bdst) {
    __shared__ float aT[F][F];  // [k][n] (transposed agg tile)
    __shared__ float lW[F][F];  // [k][j]
    int dir = blockIdx.y;
    float* out = dir ? outB : outA;
    const float* W = dir ? Wdst : Wsrc;
    const float* bias = dir ? bdst : bsrc;
    int node0 = blockIdx.x * F;
    int t = threadIdx.x;

    for (int r = 0; r < 4; ++r) {
        int idx = r * 256 + t;      // 0..1023 float4 slots
        int n = idx >> 4;           // 0..63
        int k4 = (idx & 15) * 4;
        float4 v = {0.f, 0.f, 0.f, 0.f};
        if (node0 + n < N_NODES) v = *(const float4*)&out[(size_t)(node0 + n) * F + k4];
        aT[k4 + 0][n] = v.x; aT[k4 + 1][n] = v.y; aT[k4 + 2][n] = v.z; aT[k4 + 3][n] = v.w;
        ((float4*)lW)[idx] = ((const float4*)W)[idx];
    }
    __syncthreads();

    int tx = t & 15, ty = t >> 4;
    int j4 = tx * 4, n4 = ty * 4;
    float4 bj = *(const float4*)&bias[j4];
    float4 acc0 = bj, acc1 = bj, acc2 = bj, acc3 = bj;
    #pragma unroll 8
    for (int k = 0; k < F; ++k) {
        float4 wv = *(const float4*)&lW[k][j4];
        float4 av = *(const float4*)&aT[k][n4];
        acc0.x += av.x * wv.x; acc0.y += av.x * wv.y; acc0.z += av.x * wv.z; acc0.w += av.x * wv.w;
        acc1.x += av.y * wv.x; acc1.y += av.y * wv.y; acc1.z += av.y * wv.z; acc1.w += av.y * wv.w;
        acc2.x += av.z * wv.x; acc2.y += av.z * wv.y; acc2.z += av.z * wv.z; acc2.w += av.z * wv.w;
        acc3.x += av.w * wv.x; acc3.y += av.w * wv.y; acc3.z += av.w * wv.z; acc3.w += av.w * wv.w;
    }
    float4 accs[4] = {acc0, acc1, acc2, acc3};
    #pragma unroll
    for (int i = 0; i < 4; ++i) {
        int n = node0 + n4 + i;
        if (n < N_NODES) *(float4*)&out[(size_t)n * F + j4] = accs[i];
    }
}

// ---------------- fallback path (round-1 atomic version) ----------------

__global__ __launch_bounds__(256) void scatter_fallback(const float4* __restrict__ x4,
                                                        const int* __restrict__ ei,
                                                        const float* __restrict__ ew,
                                                        float* __restrict__ aggA,
                                                        float* __restrict__ aggB) {
    int t = blockIdx.x * blockDim.x + threadIdx.x;
    int e = t >> 4;
    int lane16 = t & 15;
    if (e >= N_EDGES) return;
    int src = ei[e], dst = ei[N_EDGES + e];
    float w0 = ew[e], w1 = ew[N_EDGES + e];
    float4 v = x4[(size_t)src * 16 + lane16];
    int base = dst * F + lane16 * 4;
    atomicAdd(&aggA[base + 0], v.x * w0); atomicAdd(&aggA[base + 1], v.y * w0);
    atomicAdd(&aggA[base + 2], v.z * w0); atomicAdd(&aggA[base + 3], v.w * w0);
    atomicAdd(&aggB[base + 0], v.x * w1); atomicAdd(&aggB[base + 1], v.y * w1);
    atomicAdd(&aggB[base + 2], v.z * w1); atomicAdd(&aggB[base + 3], v.w * w1);
}

__global__ __launch_bounds__(256) void matmul_fallback(float* __restrict__ outA, float* __restrict__ outB,
                                                       const float* __restrict__ Wsrc, const float* __restrict__ Wdst,
                                                       const float* __restrict__ bsrc, const float* __restrict__ bdst) {
    __shared__ float lWs[F * F];
    __shared__ float lWd[F * F];
    for (int i = threadIdx.x; i < F * F / 4; i += blockDim.x) {
        ((float4*)lWs)[i] = ((const float4*)Wsrc)[i];
        ((float4*)lWd)[i] = ((const float4*)Wdst)[i];
    }
    __syncthreads();
    int wave = (blockIdx.x * blockDim.x + threadIdx.x) >> 6;
    int lane = threadIdx.x & 63;
    if (wave >= N_NODES) return;
    size_t rowbase = (size_t)wave * F;
    float a0 = outA[rowbase + lane], a1 = outB[rowbase + lane];
    float acc0 = bsrc[lane], acc1 = bdst[lane];
    #pragma unroll
    for (int k = 0; k < F; ++k) {
        acc0 += __shfl(a0, k) * lWs[k * F + lane];
        acc1 += __shfl(a1, k) * lWd[k * F + lane];
    }
    outA[rowbase + lane] = acc0;
    outB[rowbase + lane] = acc1;
}

// ---------------- launch ----------------

extern "C" void kernel_launch(void* const* d_in, const int* in_sizes, int n_in,
                              void* d_out, int out_size, void* d_ws, size_t ws_size,
                              hipStream_t stream) {
    const float* x    = (const float*)d_in[0];
    const int*   ei   = (const int*)d_in[1];
    const float* ew   = (const float*)d_in[2];
    const float* Wsrc = (const float*)d_in[3];
    const float* Wdst = (const float*)d_in[4];
    const float* bsrc = (const float*)d_in[5];
    const float* bdst = (const float*)d_in[6];

    float* outA = (float*)d_out;
    float* outB = (float*)d_out + (size_t)N_NODES * F;

    // ws layout (16B-aligned segments)
    const size_t OFF_COUNTS   = 0;                            // N*4
    const size_t OFF_OFF      = 400128;                       // (N+1)*4
    const size_t OFF_CURSOR   = 800512;                       // N*4
    const size_t OFF_PARTIALS = 1200640;                      // 512
    const size_t OFF_SSRC     = 1201152;                      // E*4
    const size_t OFF_SW       = 6201152;                      // E*8
    const size_t REQ          = 16201152;

    if (ws_size >= REQ) {
        char* ws = (char*)d_ws;
        int*    counts   = (int*)(ws + OFF_COUNTS);
        int*    off      = (int*)(ws + OFF_OFF);
        int*    cursor   = (int*)(ws + OFF_CURSOR);
        int*    partials = (int*)(ws + OFF_PARTIALS);
        int*    sSrc     = (int*)(ws + OFF_SSRC);
        float2* sW       = (float2*)(ws + OFF_SW);

        hipMemsetAsync(counts, 0, (size_t)N_NODES * sizeof(int), stream);

        int eblk = (N_EDGES + 255) / 256;  // 4883
        hist_kernel<<<eblk, 256, 0, stream>>>(ei, counts);
        scan_reduce_kernel<<<NBLK_SCAN, 256, 0, stream>>>(counts, partials);
        scan_partials_kernel<<<1, 64, 0, stream>>>(partials);
        scan_apply_kernel<<<NBLK_SCAN, 256, 0, stream>>>(counts, partials, off, cursor);
        permute_kernel<<<eblk, 256, 0, stream>>>(ei, ew, cursor, sSrc, sW);
        agg_kernel<<<N_NODES / 4, 256, 0, stream>>>(x, off, sSrc, sW, outA, outB);
        dim3 ggrid((N_NODES + F - 1) / F, 2);  // (1563, 2)
        gemm_kernel<<<ggrid, 256, 0, stream>>>(outA, outB, Wsrc, Wdst, bsrc, bdst);
    } else {
        // fallback: round-1 atomic path
        hipMemsetAsync(d_out, 0, (size_t)out_size * sizeof(float), stream);
        int blocks_scatter = (N_EDGES * 16 + 255) / 256;
        scatter_fallback<<<blocks_scatter, 256, 0, stream>>>((const float4*)x, ei, ew, outA, outB);
        int blocks_mm = (N_NODES * 64 + 255) / 256;
        matmul_fallback<<<blocks_mm, 256, 0, stream>>>(outA, outB, Wsrc, Wdst, bsrc, bdst);
    }
}

// Round 3
// 323.986 us; speedup vs baseline: 7.3797x; 1.1200x over previous
//
#include <hip/hip_runtime.h>

#define N_NODES 100000
#define N_EDGES 1250000
#define F 64
#define SCAN_CHUNK 1024
#define NBLK_SCAN ((N_NODES + SCAN_CHUNK - 1) / SCAN_CHUNK)  // 98
#define GPW 4  // nodes per wave in agg_kernel

// ---------------- CSR-build path ----------------

// K1: histogram of receivers.
__global__ __launch_bounds__(256) void hist_kernel(const int* __restrict__ ei,
                                                   int* __restrict__ counts) {
    int e = blockIdx.x * 256 + threadIdx.x;
    if (e < N_EDGES) atomicAdd(&counts[ei[N_EDGES + e]], 1);
}

// K2a: per-1024-chunk partial sums of counts.
__global__ __launch_bounds__(256) void scan_reduce_kernel(const int* __restrict__ counts,
                                                          int* __restrict__ partials) {
    int base = blockIdx.x * SCAN_CHUNK + threadIdx.x * 4;
    int s = 0;
    if (base + 3 < N_NODES) {
        int4 c = *(const int4*)&counts[base];
        s = c.x + c.y + c.z + c.w;
    }
    for (int d = 32; d > 0; d >>= 1) s += __shfl_down(s, d);
    __shared__ int lds[4];
    int lane = threadIdx.x & 63, wave = threadIdx.x >> 6;
    if (lane == 0) lds[wave] = s;
    __syncthreads();
    if (threadIdx.x == 0) partials[blockIdx.x] = lds[0] + lds[1] + lds[2] + lds[3];
}

// K2b: per-chunk exclusive scan; chunk base computed in-block from raw partials
// (fuses the old scan_partials kernel: 98 values, each block reduces its prefix).
__global__ __launch_bounds__(256) void scan_apply_kernel(const int* __restrict__ counts,
                                                         const int* __restrict__ partials,
                                                         int* __restrict__ off,
                                                         int* __restrict__ cursor) {
    __shared__ int sh_red[4];
    __shared__ int sh_base;
    __shared__ int wsum[4];
    int t = threadIdx.x;
    int lane = t & 63, wave = t >> 6;

    // chunk base = sum of partials[0 .. blockIdx.x)
    int pp = 0;
    if (t < blockIdx.x && t < NBLK_SCAN) pp = partials[t];
    for (int d = 32; d > 0; d >>= 1) pp += __shfl_down(pp, d);
    if (lane == 0) sh_red[wave] = pp;
    __syncthreads();
    if (t == 0) sh_base = sh_red[0] + sh_red[1] + sh_red[2] + sh_red[3];

    int base = blockIdx.x * SCAN_CHUNK + t * 4;
    int4 c = {0, 0, 0, 0};
    bool act = (base + 3 < N_NODES);
    if (act) c = *(const int4*)&counts[base];
    int s = c.x + c.y + c.z + c.w;

    int xs = s;
    for (int d = 1; d < 64; d <<= 1) {
        int y = __shfl_up(xs, d);
        if (lane >= d) xs += y;
    }
    if (lane == 63) wsum[wave] = xs;
    __syncthreads();
    int pre = xs - s;
    for (int w = 0; w < wave; ++w) pre += wsum[w];
    pre += sh_base;

    if (act) {
        int o0 = pre, o1 = o0 + c.x, o2 = o1 + c.y, o3 = o2 + c.z;
        int4 o = {o0, o1, o2, o3};
        *(int4*)&off[base] = o;
        *(int4*)&cursor[base] = o;
        if (base + 4 == N_NODES) off[N_NODES] = o3 + c.w;  // == N_EDGES
    }
}

// K3: scatter edge payloads into receiver-sorted order.
__global__ __launch_bounds__(256) void permute_kernel(const int* __restrict__ ei,
                                                      const float* __restrict__ ew,
                                                      int* __restrict__ cursor,
                                                      int* __restrict__ sSrc,
                                                      float2* __restrict__ sW) {
    int e = blockIdx.x * 256 + threadIdx.x;
    if (e >= N_EDGES) return;
    int r = ei[N_EDGES + e];
    int pos = atomicAdd(&cursor[r], 1);
    sSrc[pos] = ei[e];
    sW[pos] = make_float2(ew[e], ew[N_EDGES + e]);
}

// K4: wave handles GPW=4 consecutive nodes (contiguous CSR span) -> balanced
// (Poisson(50) per wave) flat edge loop, batched x4 with next-batch prefetch
// (8 outstanding gathers/wave). Boundary flushes are wave-uniform; each agg
// row is written exactly once. lane = feature.
__global__ __launch_bounds__(256) void agg_kernel(const float* __restrict__ x,
                                                  const int* __restrict__ off,
                                                  const int* __restrict__ sSrc,
                                                  const float2* __restrict__ sW,
                                                  float* __restrict__ outA,
                                                  float* __restrict__ outB) {
    int wv = blockIdx.x * 4 + (threadIdx.x >> 6);  // 0..24999
    int lane = threadIdx.x & 63;
    int n0 = wv * GPW;

    int b[GPW + 1];
    #pragma unroll
    for (int j = 0; j <= GPW; ++j) b[j] = off[n0 + j];

    int i = b[0];
    const int end = b[GPW];
    int cur = 0;
    int next_b = b[1];
    float accA = 0.f, accB = 0.f;

#define FLUSH() { size_t rb = (size_t)(n0 + cur) * F + lane;          \
                  outA[rb] = accA; outB[rb] = accB;                   \
                  accA = 0.f; accB = 0.f; ++cur;                      \
                  next_b = (cur < GPW) ? b[cur + 1] : 0x7fffffff; }

    int sc[4]; float2 wc[4]; float vc[4];
    if (i + 4 <= end) {
        #pragma unroll
        for (int j = 0; j < 4; ++j) { sc[j] = sSrc[i + j]; wc[j] = sW[i + j]; }
        #pragma unroll
        for (int j = 0; j < 4; ++j) vc[j] = x[(size_t)sc[j] * F + lane];
    }
    while (i + 8 <= end) {
        int sn[4]; float2 wn[4]; float vn[4];
        #pragma unroll
        for (int j = 0; j < 4; ++j) { sn[j] = sSrc[i + 4 + j]; wn[j] = sW[i + 4 + j]; }
        #pragma unroll
        for (int j = 0; j < 4; ++j) vn[j] = x[(size_t)sn[j] * F + lane];
        #pragma unroll
        for (int j = 0; j < 4; ++j) {
            while (i + j == next_b) FLUSH();
            accA += vc[j] * wc[j].x; accB += vc[j] * wc[j].y;
        }
        i += 4;
        #pragma unroll
        for (int j = 0; j < 4; ++j) { sc[j] = sn[j]; wc[j] = wn[j]; vc[j] = vn[j]; }
    }
    if (i + 4 <= end) {
        #pragma unroll
        for (int j = 0; j < 4; ++j) {
            while (i + j == next_b) FLUSH();
            accA += vc[j] * wc[j].x; accB += vc[j] * wc[j].y;
        }
        i += 4;
    }
    while (i < end) {
        while (i == next_b) FLUSH();
        int s = sSrc[i]; float2 w = sW[i];
        float v = x[(size_t)s * F + lane];
        accA += v * w.x; accB += v * w.y;
        ++i;
    }
    while (cur < GPW) FLUSH();
#undef FLUSH
}

// K5: register-tiled [64-node x 64-feat] GEMM + bias, in place on d_out.
__global__ __launch_bounds__(256) void gemm_kernel(float* __restrict__ outA,
                                                   float* __restrict__ outB,
                                                   const float* __restrict__ Wsrc,
                                                   const float* __restrict__ Wdst,
                                                   const float* __restrict__ bsrc,
                                                   const float* __restrict__ bdst) {
    __shared__ float aT[F][F];  // [k][n]
    __shared__ float lW[F][F];  // [k][j]
    int dir = blockIdx.y;
    float* out = dir ? outB : outA;
    const float* W = dir ? Wdst : Wsrc;
    const float* bias = dir ? bdst : bsrc;
    int node0 = blockIdx.x * F;
    int t = threadIdx.x;

    for (int r = 0; r < 4; ++r) {
        int idx = r * 256 + t;
        int n = idx >> 4;
        int k4 = (idx & 15) * 4;
        float4 v = {0.f, 0.f, 0.f, 0.f};
        if (node0 + n < N_NODES) v = *(const float4*)&out[(size_t)(node0 + n) * F + k4];
        aT[k4 + 0][n] = v.x; aT[k4 + 1][n] = v.y; aT[k4 + 2][n] = v.z; aT[k4 + 3][n] = v.w;
        ((float4*)lW)[idx] = ((const float4*)W)[idx];
    }
    __syncthreads();

    int tx = t & 15, ty = t >> 4;
    int j4 = tx * 4, n4 = ty * 4;
    float4 bj = *(const float4*)&bias[j4];
    float4 acc0 = bj, acc1 = bj, acc2 = bj, acc3 = bj;
    #pragma unroll 8
    for (int k = 0; k < F; ++k) {
        float4 wv = *(const float4*)&lW[k][j4];
        float4 av = *(const float4*)&aT[k][n4];
        acc0.x += av.x * wv.x; acc0.y += av.x * wv.y; acc0.z += av.x * wv.z; acc0.w += av.x * wv.w;
        acc1.x += av.y * wv.x; acc1.y += av.y * wv.y; acc1.z += av.y * wv.z; acc1.w += av.y * wv.w;
        acc2.x += av.z * wv.x; acc2.y += av.z * wv.y; acc2.z += av.z * wv.z; acc2.w += av.z * wv.w;
        acc3.x += av.w * wv.x; acc3.y += av.w * wv.y; acc3.z += av.w * wv.z; acc3.w += av.w * wv.w;
    }
    float4 accs[4] = {acc0, acc1, acc2, acc3};
    #pragma unroll
    for (int i = 0; i < 4; ++i) {
        int n = node0 + n4 + i;
        if (n < N_NODES) *(float4*)&out[(size_t)n * F + j4] = accs[i];
    }
}

// ---------------- fallback path (round-1 atomic version) ----------------

__global__ __launch_bounds__(256) void scatter_fallback(const float4* __restrict__ x4,
                                                        const int* __restrict__ ei,
                                                        const float* __restrict__ ew,
                                                        float* __restrict__ aggA,
                                                        float* __restrict__ aggB) {
    int t = blockIdx.x * blockDim.x + threadIdx.x;
    int e = t >> 4;
    int lane16 = t & 15;
    if (e >= N_EDGES) return;
    int src = ei[e], dst = ei[N_EDGES + e];
    float w0 = ew[e], w1 = ew[N_EDGES + e];
    float4 v = x4[(size_t)src * 16 + lane16];
    int base = dst * F + lane16 * 4;
    atomicAdd(&aggA[base + 0], v.x * w0); atomicAdd(&aggA[base + 1], v.y * w0);
    atomicAdd(&aggA[base + 2], v.z * w0); atomicAdd(&aggA[base + 3], v.w * w0);
    atomicAdd(&aggB[base + 0], v.x * w1); atomicAdd(&aggB[base + 1], v.y * w1);
    atomicAdd(&aggB[base + 2], v.z * w1); atomicAdd(&aggB[base + 3], v.w * w1);
}

__global__ __launch_bounds__(256) void matmul_fallback(float* __restrict__ outA, float* __restrict__ outB,
                                                       const float* __restrict__ Wsrc, const float* __restrict__ Wdst,
                                                       const float* __restrict__ bsrc, const float* __restrict__ bdst) {
    __shared__ float lWs[F * F];
    __shared__ float lWd[F * F];
    for (int i = threadIdx.x; i < F * F / 4; i += blockDim.x) {
        ((float4*)lWs)[i] = ((const float4*)Wsrc)[i];
        ((float4*)lWd)[i] = ((const float4*)Wdst)[i];
    }
    __syncthreads();
    int wave = (blockIdx.x * blockDim.x + threadIdx.x) >> 6;
    int lane = threadIdx.x & 63;
    if (wave >= N_NODES) return;
    size_t rowbase = (size_t)wave * F;
    float a0 = outA[rowbase + lane], a1 = outB[rowbase + lane];
    float acc0 = bsrc[lane], acc1 = bdst[lane];
    #pragma unroll
    for (int k = 0; k < F; ++k) {
        acc0 += __shfl(a0, k) * lWs[k * F + lane];
        acc1 += __shfl(a1, k) * lWd[k * F + lane];
    }
    outA[rowbase + lane] = acc0;
    outB[rowbase + lane] = acc1;
}

// ---------------- launch ----------------

extern "C" void kernel_launch(void* const* d_in, const int* in_sizes, int n_in,
                              void* d_out, int out_size, void* d_ws, size_t ws_size,
                              hipStream_t stream) {
    const float* x    = (const float*)d_in[0];
    const int*   ei   = (const int*)d_in[1];
    const float* ew   = (const float*)d_in[2];
    const float* Wsrc = (const float*)d_in[3];
    const float* Wdst = (const float*)d_in[4];
    const float* bsrc = (const float*)d_in[5];
    const float* bdst = (const float*)d_in[6];

    float* outA = (float*)d_out;
    float* outB = (float*)d_out + (size_t)N_NODES * F;

    // ws layout (same footprint as round 2: proven to fit)
    const size_t OFF_COUNTS   = 0;
    const size_t OFF_OFF      = 400128;
    const size_t OFF_CURSOR   = 800512;
    const size_t OFF_PARTIALS = 1200640;
    const size_t OFF_SSRC     = 1201152;
    const size_t OFF_SW       = 6201152;
    const size_t REQ          = 16201152;

    if (ws_size >= REQ) {
        char* ws = (char*)d_ws;
        int*    counts   = (int*)(ws + OFF_COUNTS);
        int*    off      = (int*)(ws + OFF_OFF);
        int*    cursor   = (int*)(ws + OFF_CURSOR);
        int*    partials = (int*)(ws + OFF_PARTIALS);
        int*    sSrc     = (int*)(ws + OFF_SSRC);
        float2* sW       = (float2*)(ws + OFF_SW);

        hipMemsetAsync(counts, 0, (size_t)N_NODES * sizeof(int), stream);

        int eblk = (N_EDGES + 255) / 256;  // 4883
        hist_kernel<<<eblk, 256, 0, stream>>>(ei, counts);
        scan_reduce_kernel<<<NBLK_SCAN, 256, 0, stream>>>(counts, partials);
        scan_apply_kernel<<<NBLK_SCAN, 256, 0, stream>>>(counts, partials, off, cursor);
        permute_kernel<<<eblk, 256, 0, stream>>>(ei, ew, cursor, sSrc, sW);
        agg_kernel<<<N_NODES / (GPW * 4), 256, 0, stream>>>(x, off, sSrc, sW, outA, outB);
        dim3 ggrid((N_NODES + F - 1) / F, 2);
        gemm_kernel<<<ggrid, 256, 0, stream>>>(outA, outB, Wsrc, Wdst, bsrc, bdst);
    } else {
        hipMemsetAsync(d_out, 0, (size_t)out_size * sizeof(float), stream);
        int blocks_scatter = (N_EDGES * 16 + 255) / 256;
        scatter_fallback<<<blocks_scatter, 256, 0, stream>>>((const float4*)x, ei, ew, outA, outB);
        int blocks_mm = (N_NODES * 64 + 255) / 256;
        matmul_fallback<<<blocks_mm, 256, 0, stream>>>(outA, outB, Wsrc, Wdst, bsrc, bdst);
    }
}

// Round 4
// 317.094 us; speedup vs baseline: 7.5401x; 1.0217x over previous
//
#include <hip/hip_runtime.h>
#include <hip/hip_fp16.h>

#define N_NODES 100000
#define N_EDGES 1250000
#define F 64
#define SCAN_CHUNK 1024
#define NBLK_SCAN ((N_NODES + SCAN_CHUNK - 1) / SCAN_CHUNK)  // 98
#define GPW 4    // nodes per wave
#define NPB 32   // nodes per block (8 waves * GPW)
#define TP  33   // tile pad: column writes (lane*33+n)%32 = (lane+n)%32 -> conflict-free

// ---------------- CSR-build path ----------------

// K1: histogram of receivers.
__global__ __launch_bounds__(256) void hist_kernel(const int* __restrict__ ei,
                                                   int* __restrict__ counts) {
    int e = blockIdx.x * 256 + threadIdx.x;
    if (e < N_EDGES) atomicAdd(&counts[ei[N_EDGES + e]], 1);
}

// K2a: per-1024-chunk partial sums of counts.
__global__ __launch_bounds__(256) void scan_reduce_kernel(const int* __restrict__ counts,
                                                          int* __restrict__ partials) {
    int base = blockIdx.x * SCAN_CHUNK + threadIdx.x * 4;
    int s = 0;
    if (base + 3 < N_NODES) {
        int4 c = *(const int4*)&counts[base];
        s = c.x + c.y + c.z + c.w;
    }
    for (int d = 32; d > 0; d >>= 1) s += __shfl_down(s, d);
    __shared__ int lds[4];
    int lane = threadIdx.x & 63, wave = threadIdx.x >> 6;
    if (lane == 0) lds[wave] = s;
    __syncthreads();
    if (threadIdx.x == 0) partials[blockIdx.x] = lds[0] + lds[1] + lds[2] + lds[3];
}

// K2b: per-chunk exclusive scan; chunk base reduced in-block from raw partials.
__global__ __launch_bounds__(256) void scan_apply_kernel(const int* __restrict__ counts,
                                                         const int* __restrict__ partials,
                                                         int* __restrict__ off,
                                                         int* __restrict__ cursor) {
    __shared__ int sh_red[4];
    __shared__ int sh_base;
    __shared__ int wsum[4];
    int t = threadIdx.x;
    int lane = t & 63, wave = t >> 6;

    int pp = 0;
    if (t < blockIdx.x && t < NBLK_SCAN) pp = partials[t];
    for (int d = 32; d > 0; d >>= 1) pp += __shfl_down(pp, d);
    if (lane == 0) sh_red[wave] = pp;
    __syncthreads();
    if (t == 0) sh_base = sh_red[0] + sh_red[1] + sh_red[2] + sh_red[3];

    int base = blockIdx.x * SCAN_CHUNK + t * 4;
    int4 c = {0, 0, 0, 0};
    bool act = (base + 3 < N_NODES);
    if (act) c = *(const int4*)&counts[base];
    int s = c.x + c.y + c.z + c.w;

    int xs = s;
    for (int d = 1; d < 64; d <<= 1) {
        int y = __shfl_up(xs, d);
        if (lane >= d) xs += y;
    }
    if (lane == 63) wsum[wave] = xs;
    __syncthreads();
    int pre = xs - s;
    for (int w = 0; w < wave; ++w) pre += wsum[w];
    pre += sh_base;

    if (act) {
        int o0 = pre, o1 = o0 + c.x, o2 = o1 + c.y, o3 = o2 + c.z;
        int4 o = {o0, o1, o2, o3};
        *(int4*)&off[base] = o;
        *(int4*)&cursor[base] = o;
        if (base + 4 == N_NODES) off[N_NODES] = o3 + c.w;  // == N_EDGES
    }
}

// K3: scatter packed payload {src:int, (w0,w1):half2} -> ONE 8B store per edge.
__global__ __launch_bounds__(256) void permute_kernel(const int* __restrict__ ei,
                                                      const float* __restrict__ ew,
                                                      int* __restrict__ cursor,
                                                      int2* __restrict__ pay) {
    int e = blockIdx.x * 256 + threadIdx.x;
    if (e >= N_EDGES) return;
    int r = ei[N_EDGES + e];
    int pos = atomicAdd(&cursor[r], 1);
    __half2 h = __floats2half2_rn(ew[e], ew[N_EDGES + e]);
    int2 p;
    p.x = ei[e];
    p.y = *(const int*)&h;
    pay[pos] = p;
}

// K4: fused aggregation + GEMM. 512 threads = 8 waves x GPW=4 nodes = 32 nodes/block.
// Edge loop (balanced contiguous CSR spans, x4 batched with next-batch prefetch)
// flushes agg rows into transposed LDS tiles [k][n] (pad 33 -> conflict-free column
// writes). After one barrier, 256 threads do the register-tiled 4n x 4j GEMM per
// direction (A from LDS, W/bias from global/L1) and write final out coalesced.
__global__ __launch_bounds__(512, 4) void agg_gemm_kernel(
    const float* __restrict__ x, const int* __restrict__ off,
    const int2* __restrict__ pay,
    const float* __restrict__ Wsrc, const float* __restrict__ Wdst,
    const float* __restrict__ bsrc, const float* __restrict__ bdst,
    float* __restrict__ outA, float* __restrict__ outB)
{
    __shared__ float tA[F * TP];
    __shared__ float tB[F * TP];
    int t = threadIdx.x;
    int w = t >> 6;        // wave in block: 0..7
    int lane = t & 63;     // feature k
    int n0 = blockIdx.x * NPB + w * GPW;
    int nIB0 = w * GPW;

    int b[GPW + 1];
    #pragma unroll
    for (int j = 0; j <= GPW; ++j) b[j] = off[n0 + j];

    int i = b[0];
    const int end = b[GPW];
    int cur = 0;
    int next_b = b[1];
    float accA = 0.f, accB = 0.f;

#define FLUSH() { tA[lane * TP + nIB0 + cur] = accA;                  \
                  tB[lane * TP + nIB0 + cur] = accB;                  \
                  accA = 0.f; accB = 0.f; ++cur;                      \
                  next_b = (cur < GPW) ? b[cur + 1] : 0x7fffffff; }

    int2 pc[4]; float vc[4];
    if (i + 4 <= end) {
        #pragma unroll
        for (int j = 0; j < 4; ++j) pc[j] = pay[i + j];
        #pragma unroll
        for (int j = 0; j < 4; ++j) vc[j] = x[(size_t)pc[j].x * F + lane];
    }
    while (i + 8 <= end) {
        int2 pn[4]; float vn[4];
        #pragma unroll
        for (int j = 0; j < 4; ++j) pn[j] = pay[i + 4 + j];
        #pragma unroll
        for (int j = 0; j < 4; ++j) vn[j] = x[(size_t)pn[j].x * F + lane];
        #pragma unroll
        for (int j = 0; j < 4; ++j) {
            while (i + j == next_b) FLUSH();
            float2 wv = __half22float2(*(const __half2*)&pc[j].y);
            accA += vc[j] * wv.x; accB += vc[j] * wv.y;
        }
        i += 4;
        #pragma unroll
        for (int j = 0; j < 4; ++j) { pc[j] = pn[j]; vc[j] = vn[j]; }
    }
    if (i + 4 <= end) {
        #pragma unroll
        for (int j = 0; j < 4; ++j) {
            while (i + j == next_b) FLUSH();
            float2 wv = __half22float2(*(const __half2*)&pc[j].y);
            accA += vc[j] * wv.x; accB += vc[j] * wv.y;
        }
        i += 4;
    }
    while (i < end) {
        while (i == next_b) FLUSH();
        int2 p = pay[i];
        float2 wv = __half22float2(*(const __half2*)&p.y);
        float v = x[(size_t)p.x * F + lane];
        accA += v * wv.x; accB += v * wv.y;
        ++i;
    }
    while (cur < GPW) FLUSH();
#undef FLUSH

    __syncthreads();

    // GEMM phase: 256 active threads; dir = t>>7; 4 nodes x 4 feats per thread.
    if (t < 256) {
        int dir = t >> 7;
        int tx = t & 15, ty = (t >> 4) & 7;
        int j4 = tx * 4, n4 = ty * 4;
        const float* W    = dir ? Wdst : Wsrc;
        const float* bias = dir ? bdst : bsrc;
        const float* tile = dir ? tB : tA;
        float* out        = dir ? outB : outA;

        float4 bj = *(const float4*)&bias[j4];
        float4 a0 = bj, a1 = bj, a2 = bj, a3 = bj;
        #pragma unroll 8
        for (int k = 0; k < F; ++k) {
            float4 wv = *(const float4*)&W[k * F + j4];
            float v0 = tile[k * TP + n4 + 0];
            float v1 = tile[k * TP + n4 + 1];
            float v2 = tile[k * TP + n4 + 2];
            float v3 = tile[k * TP + n4 + 3];
            a0.x += v0 * wv.x; a0.y += v0 * wv.y; a0.z += v0 * wv.z; a0.w += v0 * wv.w;
            a1.x += v1 * wv.x; a1.y += v1 * wv.y; a1.z += v1 * wv.z; a1.w += v1 * wv.w;
            a2.x += v2 * wv.x; a2.y += v2 * wv.y; a2.z += v2 * wv.z; a2.w += v2 * wv.w;
            a3.x += v3 * wv.x; a3.y += v3 * wv.y; a3.z += v3 * wv.z; a3.w += v3 * wv.w;
        }
        int nb = blockIdx.x * NPB + n4;
        *(float4*)&out[(size_t)(nb + 0) * F + j4] = a0;
        *(float4*)&out[(size_t)(nb + 1) * F + j4] = a1;
        *(float4*)&out[(size_t)(nb + 2) * F + j4] = a2;
        *(float4*)&out[(size_t)(nb + 3) * F + j4] = a3;
    }
}

// ---------------- fallback path (round-1 atomic version) ----------------

__global__ __launch_bounds__(256) void scatter_fallback(const float4* __restrict__ x4,
                                                        const int* __restrict__ ei,
                                                        const float* __restrict__ ew,
                                                        float* __restrict__ aggA,
                                                        float* __restrict__ aggB) {
    int t = blockIdx.x * blockDim.x + threadIdx.x;
    int e = t >> 4;
    int lane16 = t & 15;
    if (e >= N_EDGES) return;
    int src = ei[e], dst = ei[N_EDGES + e];
    float w0 = ew[e], w1 = ew[N_EDGES + e];
    float4 v = x4[(size_t)src * 16 + lane16];
    int base = dst * F + lane16 * 4;
    atomicAdd(&aggA[base + 0], v.x * w0); atomicAdd(&aggA[base + 1], v.y * w0);
    atomicAdd(&aggA[base + 2], v.z * w0); atomicAdd(&aggA[base + 3], v.w * w0);
    atomicAdd(&aggB[base + 0], v.x * w1); atomicAdd(&aggB[base + 1], v.y * w1);
    atomicAdd(&aggB[base + 2], v.z * w1); atomicAdd(&aggB[base + 3], v.w * w1);
}

__global__ __launch_bounds__(256) void matmul_fallback(float* __restrict__ outA, float* __restrict__ outB,
                                                       const float* __restrict__ Wsrc, const float* __restrict__ Wdst,
                                                       const float* __restrict__ bsrc, const float* __restrict__ bdst) {
    __shared__ float lWs[F * F];
    __shared__ float lWd[F * F];
    for (int i = threadIdx.x; i < F * F / 4; i += blockDim.x) {
        ((float4*)lWs)[i] = ((const float4*)Wsrc)[i];
        ((float4*)lWd)[i] = ((const float4*)Wdst)[i];
    }
    __syncthreads();
    int wave = (blockIdx.x * blockDim.x + threadIdx.x) >> 6;
    int lane = threadIdx.x & 63;
    if (wave >= N_NODES) return;
    size_t rowbase = (size_t)wave * F;
    float a0 = outA[rowbase + lane], a1 = outB[rowbase + lane];
    float acc0 = bsrc[lane], acc1 = bdst[lane];
    #pragma unroll
    for (int k = 0; k < F; ++k) {
        acc0 += __shfl(a0, k) * lWs[k * F + lane];
        acc1 += __shfl(a1, k) * lWd[k * F + lane];
    }
    outA[rowbase + lane] = acc0;
    outB[rowbase + lane] = acc1;
}

// ---------------- launch ----------------

extern "C" void kernel_launch(void* const* d_in, const int* in_sizes, int n_in,
                              void* d_out, int out_size, void* d_ws, size_t ws_size,
                              hipStream_t stream) {
    const float* x    = (const float*)d_in[0];
    const int*   ei   = (const int*)d_in[1];
    const float* ew   = (const float*)d_in[2];
    const float* Wsrc = (const float*)d_in[3];
    const float* Wdst = (const float*)d_in[4];
    const float* bsrc = (const float*)d_in[5];
    const float* bdst = (const float*)d_in[6];

    float* outA = (float*)d_out;
    float* outB = (float*)d_out + (size_t)N_NODES * F;

    // ws layout (8B-aligned segments)
    const size_t OFF_COUNTS   = 0;         // N*4      = 400000 -> pad 400128
    const size_t OFF_OFF      = 400128;    // (N+1)*4  = 400004 -> pad 400512
    const size_t OFF_CURSOR   = 800640;    // N*4      -> pad 400128
    const size_t OFF_PARTIALS = 1200768;   // 512
    const size_t OFF_PAY      = 1201280;   // E*8 = 10,000,000
    const size_t REQ          = 11201280;

    if (ws_size >= REQ) {
        char* ws = (char*)d_ws;
        int*  counts   = (int*)(ws + OFF_COUNTS);
        int*  off      = (int*)(ws + OFF_OFF);
        int*  cursor   = (int*)(ws + OFF_CURSOR);
        int*  partials = (int*)(ws + OFF_PARTIALS);
        int2* pay      = (int2*)(ws + OFF_PAY);

        hipMemsetAsync(counts, 0, (size_t)N_NODES * sizeof(int), stream);

        int eblk = (N_EDGES + 255) / 256;  // 4883
        hist_kernel<<<eblk, 256, 0, stream>>>(ei, counts);
        scan_reduce_kernel<<<NBLK_SCAN, 256, 0, stream>>>(counts, partials);
        scan_apply_kernel<<<NBLK_SCAN, 256, 0, stream>>>(counts, partials, off, cursor);
        permute_kernel<<<eblk, 256, 0, stream>>>(ei, ew, cursor, pay);
        agg_gemm_kernel<<<N_NODES / NPB, 512, 0, stream>>>(
            x, off, pay, Wsrc, Wdst, bsrc, bdst, outA, outB);
    } else {
        hipMemsetAsync(d_out, 0, (size_t)out_size * sizeof(float), stream);
        int blocks_scatter = (N_EDGES * 16 + 255) / 256;
        scatter_fallback<<<blocks_scatter, 256, 0, stream>>>((const float4*)x, ei, ew, outA, outB);
        int blocks_mm = (N_NODES * 64 + 255) / 256;
        matmul_fallback<<<blocks_mm, 256, 0, stream>>>(outA, outB, Wsrc, Wdst, bsrc, bdst);
    }
}